// Round 1
// baseline (97.906 us; speedup 1.0000x reference)
//
#include <hip/hip_runtime.h>
#include <hip/hip_bf16.h>

#define NBATCH 8
#define BROWS 256
#define KDIM 512
#define HIDD 512
#define GDIM 2048

typedef float f32x4 __attribute__((ext_vector_type(4)));
typedef __bf16 bf16x8 __attribute__((ext_vector_type(8)));

__device__ __forceinline__ unsigned fenc(float f) {
    unsigned u = __float_as_uint(f);
    return (u & 0x80000000u) ? ~u : (u | 0x80000000u);
}
__device__ __forceinline__ float fdec(unsigned e) {
    unsigned u = (e & 0x80000000u) ? (e & 0x7fffffffu) : ~e;
    return __uint_as_float(u);
}
__device__ __forceinline__ unsigned umaxu(unsigned a, unsigned b) { return a > b ? a : b; }

// quant(pact(x,a), 8, a)  -- all a's are powers of 2 so /a, *a are exact
__device__ __forceinline__ float qpact(float x, float a) {
    float ax = fabsf(x);
    float p  = copysignf(0.5f * (ax - fabsf(ax - a) + a), x);
    float x01 = p / a;
    x01 = fminf(fmaxf(x01, -0.9921875f), 0.9921875f);
    return (rintf(x01 * 128.f) * 0.0078125f) * a;
}
// quant(x, 8, 1.0)
__device__ __forceinline__ float q1(float x) {
    float x01 = fminf(fmaxf(x, -0.9921875f), 0.9921875f);
    return rintf(x01 * 128.f) * 0.0078125f;
}
__device__ __forceinline__ float sigmf(float x) { return 1.0f / (1.0f + expf(-x)); }

__global__ void k_init(unsigned* m) { if (threadIdx.x < 4) m[threadIdx.x] = 0u; }

__global__ void k_max(const float* __restrict__ w_ih, const float* __restrict__ w_hh,
                      const float* __restrict__ b_ih, const float* __restrict__ b_hh,
                      unsigned* __restrict__ omax) {
    int which = blockIdx.y;
    const float* src = which == 0 ? w_ih : which == 1 ? w_hh : which == 2 ? b_ih : b_hh;
    int n4 = (which < 2 ? NBATCH * KDIM * GDIM : NBATCH * GDIM) >> 2;
    unsigned best = 0u;
    int stride = gridDim.x * blockDim.x;
    for (int i = blockIdx.x * blockDim.x + threadIdx.x; i < n4; i += stride) {
        float4 v = ((const float4*)src)[i];
        best = umaxu(best, fenc(v.x)); best = umaxu(best, fenc(v.y));
        best = umaxu(best, fenc(v.z)); best = umaxu(best, fenc(v.w));
    }
    #pragma unroll
    for (int off = 32; off > 0; off >>= 1)
        best = umaxu(best, (unsigned)__shfl_down((int)best, off, 64));
    __shared__ unsigned red[4];
    int lane = threadIdx.x & 63, wv = threadIdx.x >> 6;
    if (lane == 0) red[wv] = best;
    __syncthreads();
    if (threadIdx.x == 0) {
        unsigned b2 = umaxu(umaxu(red[0], red[1]), umaxu(red[2], red[3]));
        atomicMax(&omax[which], b2);
    }
}

__global__ void k_prep(const float* __restrict__ input, const float* __restrict__ hx,
                       const float* __restrict__ bih, const float* __restrict__ bhh,
                       const float* __restrict__ nbih, const float* __restrict__ nbhh,
                       const float* __restrict__ a1, const unsigned* __restrict__ maxes,
                       __hip_bfloat16* __restrict__ xqh, __hip_bfloat16* __restrict__ hxh,
                       __hip_bfloat16* __restrict__ hxl, float* __restrict__ bias_comb) {
    const int NX = NBATCH * BROWS * KDIM;
    const int NH = NBATCH * BROWS * HIDD;
    const int NBC = NBATCH * GDIM;
    int total = NX + NH + NBC;
    int stride = gridDim.x * blockDim.x;
    for (int i = blockIdx.x * blockDim.x + threadIdx.x; i < total; i += stride) {
        if (i < NX) {
            int nb = i >> 17;              // /(256*512)
            int rem = i & 131071;
            float v = qpact(input[rem], a1[nb]);
            xqh[i] = __float2bfloat16(v);  // exact: integers <=127 for a1=128
        } else if (i < NX + NH) {
            int j = i - NX;
            float h = hx[j];
            __hip_bfloat16 hi = __float2bfloat16(h);
            hxh[j] = hi;
            hxl[j] = __float2bfloat16(h - __bfloat162float(hi));
        } else {
            int j = i - NX - NH;
            float mb_ih = fdec(maxes[2]);
            float mb_hh = fdec(maxes[3]);
            // mimic ref op order: bq + (noise*max)*0.05
            bias_comb[j] = q1(bih[j]) + (nbih[j] * mb_ih) * 0.05f
                         + q1(bhh[j]) + (nbhh[j] * mb_hh) * 0.05f;
        }
    }
}

__global__ __launch_bounds__(512) void k_gemm(
    const float* __restrict__ w_ih, const float* __restrict__ w_hh,
    const float* __restrict__ n_ih, const float* __restrict__ n_hh,
    const __hip_bfloat16* __restrict__ xqh, const __hip_bfloat16* __restrict__ hxh,
    const __hip_bfloat16* __restrict__ hxl,
    const float* __restrict__ bias_comb, const float* __restrict__ cx,
    const float* __restrict__ a3, const float* __restrict__ a4, const float* __restrict__ a5,
    const float* __restrict__ a6, const float* __restrict__ a7, const float* __restrict__ a8,
    const float* __restrict__ a9, const float* __restrict__ a10, const float* __restrict__ a11,
    const unsigned* __restrict__ maxes,
    float* __restrict__ out_h, float* __restrict__ out_c)
{
    // B tiles only: 4 matrices [64 cols][32 k] bf16, padded rows (40) -> 20 KB
    __shared__ __hip_bfloat16 Bsm[4][64][40];

    int tid = threadIdx.x;
    int lane = tid & 63, wv = tid >> 6;
    int nb = blockIdx.x >> 5;       // 8 batches
    int cb = blockIdx.x & 31;       // 32 column-blocks of 16 HID cols

    const float* wih_b = w_ih + nb * KDIM * GDIM;
    const float* whh_b = w_hh + nb * KDIM * GDIM;
    const float* nih_b = n_ih + nb * KDIM * GDIM;
    const float* nhh_b = n_hh + nb * KDIM * GDIM;
    const __hip_bfloat16* xq_b = xqh + nb * BROWS * KDIM;
    const __hip_bfloat16* hh_b = hxh + nb * BROWS * KDIM;
    const __hip_bfloat16* hl_b = hxl + nb * BROWS * KDIM;

    float c_ih = fdec(maxes[0]);
    float c_hh = fdec(maxes[1]);

    f32x4 acc[2][4] = {};

    int lh = lane & 15;
    int lk = (lane >> 4) << 3;      // k offset 0/8/16/24
    int m0 = wv << 5;               // 32 rows per wave

    for (int k0 = 0; k0 < KDIM; k0 += 32) {
        __syncthreads();
        // stage + convert weights: 2048 (k,n) elems, 4 per thread
        #pragma unroll
        for (int t = 0; t < 4; ++t) {
            int id = tid + (t << 9);
            int n = id & 63;
            int k = id >> 6;
            int g = n >> 4;
            int col = (g << 9) + (cb << 4) + (n & 15);
            int gidx = (k0 + k) * GDIM + col;
            float w1 = wih_b[gidx], z1 = nih_b[gidx];
            float wq1 = rintf(fminf(fmaxf(w1, -0.9921875f), 0.9921875f) * 128.f) * 0.0078125f;
            float e1 = wq1 + (z1 * c_ih) * 0.05f;
            __hip_bfloat16 h1 = __float2bfloat16(e1);
            Bsm[0][n][k] = h1;
            Bsm[1][n][k] = __float2bfloat16(e1 - __bfloat162float(h1));
            float w2 = whh_b[gidx], z2 = nhh_b[gidx];
            float wq2 = rintf(fminf(fmaxf(w2, -0.9921875f), 0.9921875f) * 128.f) * 0.0078125f;
            float e2 = wq2 + (z2 * c_hh) * 0.05f;
            __hip_bfloat16 h2 = __float2bfloat16(e2);
            Bsm[2][n][k] = h2;
            Bsm[3][n][k] = __float2bfloat16(e2 - __bfloat162float(h2));
        }
        __syncthreads();

        // A fragments straight from global (L2-resident, no intra-block reuse)
        bf16x8 ax[2], ah[2], al[2];
        #pragma unroll
        for (int mf = 0; mf < 2; ++mf) {
            int r = m0 + (mf << 4) + lh;
            int aoff = r * KDIM + k0 + lk;
            ax[mf] = *(const bf16x8*)(xq_b + aoff);
            ah[mf] = *(const bf16x8*)(hh_b + aoff);
            al[mf] = *(const bf16x8*)(hl_b + aoff);
        }
        bf16x8 b0[4], b1[4], b2[4], b3[4];
        #pragma unroll
        for (int nf = 0; nf < 4; ++nf) {
            int n = (nf << 4) + lh;
            b0[nf] = *(const bf16x8*)&Bsm[0][n][lk];
            b1[nf] = *(const bf16x8*)&Bsm[1][n][lk];
            b2[nf] = *(const bf16x8*)&Bsm[2][n][lk];
            b3[nf] = *(const bf16x8*)&Bsm[3][n][lk];
        }
        #pragma unroll
        for (int mf = 0; mf < 2; ++mf)
            #pragma unroll
            for (int nf = 0; nf < 4; ++nf) {
                acc[mf][nf] = __builtin_amdgcn_mfma_f32_16x16x32_bf16(ax[mf], b0[nf], acc[mf][nf], 0, 0, 0);
                acc[mf][nf] = __builtin_amdgcn_mfma_f32_16x16x32_bf16(ax[mf], b1[nf], acc[mf][nf], 0, 0, 0);
                acc[mf][nf] = __builtin_amdgcn_mfma_f32_16x16x32_bf16(ah[mf], b2[nf], acc[mf][nf], 0, 0, 0);
                acc[mf][nf] = __builtin_amdgcn_mfma_f32_16x16x32_bf16(ah[mf], b3[nf], acc[mf][nf], 0, 0, 0);
                acc[mf][nf] = __builtin_amdgcn_mfma_f32_16x16x32_bf16(al[mf], b2[nf], acc[mf][nf], 0, 0, 0);
            }
    }

    // fused epilogue: n-frag nf == gate index (i,j,f,o); all gates in-lane
    int hcol = (cb << 4) + lh;
    float A3 = a3[nb], A4 = a4[nb], A5 = a5[nb], A6 = a6[nb], A7 = a7[nb];
    float A8 = a8[nb], A9 = a9[nb], A10 = a10[nb], A11 = a11[nb];
    float bc_i = bias_comb[nb * GDIM + hcol];
    float bc_j = bias_comb[nb * GDIM + 512 + hcol];
    float bc_f = bias_comb[nb * GDIM + 1024 + hcol];
    float bc_o = bias_comb[nb * GDIM + 1536 + hcol];
    #pragma unroll
    for (int mf = 0; mf < 2; ++mf)
        #pragma unroll
        for (int rg = 0; rg < 4; ++rg) {
            int r = m0 + (mf << 4) + ((lane >> 4) << 2) + rg;
            float gi = acc[mf][0][rg] + bc_i;
            float gj = acc[mf][1][rg] + bc_j;
            float gf = acc[mf][2][rg] + bc_f;
            float go = acc[mf][3][rg] + bc_o;
            float fg = qpact(sigmf(gf), A3);
            float ig = qpact(sigmf(gi), A4);
            float act = qpact(tanhf(gj), A5);
            float og = qpact(sigmf(go), A6);
            int oidx = (nb * BROWS + r) * HIDD + hcol;
            float cv = cx[oidx];
            float gated = qpact(cv * fg, A7);
            float actin = qpact(ig * act, A8);
            float ncv = qpact(gated + actin, A9);
            float acv = qpact(tanhf(ncv), A10);
            float nhv = qpact(acv * og, A11);
            out_h[oidx] = nhv;
            out_c[oidx] = ncv;
        }
}

extern "C" void kernel_launch(void* const* d_in, const int* in_sizes, int n_in,
                              void* d_out, int out_size, void* d_ws, size_t ws_size,
                              hipStream_t stream) {
    const float* input = (const float*)d_in[0];
    const float* hx    = (const float*)d_in[1];
    const float* cx    = (const float*)d_in[2];
    const float* w_ih  = (const float*)d_in[3];
    const float* w_hh  = (const float*)d_in[4];
    const float* b_ih  = (const float*)d_in[5];
    const float* b_hh  = (const float*)d_in[6];
    const float* n_wih = (const float*)d_in[7];
    const float* n_whh = (const float*)d_in[8];
    const float* n_bih = (const float*)d_in[9];
    const float* n_bhh = (const float*)d_in[10];
    const float* a1  = (const float*)d_in[11];
    const float* a3  = (const float*)d_in[12];
    const float* a4  = (const float*)d_in[13];
    const float* a5  = (const float*)d_in[14];
    const float* a6  = (const float*)d_in[15];
    const float* a7  = (const float*)d_in[16];
    const float* a8  = (const float*)d_in[17];
    const float* a9  = (const float*)d_in[18];
    const float* a10 = (const float*)d_in[19];
    const float* a11 = (const float*)d_in[20];

    float* out_h = (float*)d_out;
    float* out_c = out_h + NBATCH * BROWS * HIDD;

    char* ws = (char*)d_ws;
    unsigned* maxes = (unsigned*)ws;
    __hip_bfloat16* xqh = (__hip_bfloat16*)(ws + 256);
    __hip_bfloat16* hxh = (__hip_bfloat16*)(ws + 256 + 2097152);
    __hip_bfloat16* hxl = (__hip_bfloat16*)(ws + 256 + 2 * 2097152);
    float* bias_comb    = (float*)(ws + 256 + 3 * 2097152);

    k_init<<<1, 64, 0, stream>>>(maxes);
    k_max<<<dim3(256, 4), 256, 0, stream>>>(w_ih, w_hh, b_ih, b_hh, maxes);
    k_prep<<<2048, 256, 0, stream>>>(input, hx, b_ih, b_hh, n_bih, n_bhh, a1, maxes,
                                     xqh, hxh, hxl, bias_comb);
    k_gemm<<<NBATCH * 32, 512, 0, stream>>>(w_ih, w_hh, n_wih, n_whh, xqh, hxh, hxl,
                                            bias_comb, cx,
                                            a3, a4, a5, a6, a7, a8, a9, a10, a11,
                                            maxes, out_h, out_c);
}

// Round 2
// 80.192 us; speedup vs baseline: 1.2209x; 1.2209x over previous
//
#include <hip/hip_runtime.h>
#include <hip/hip_bf16.h>

#define NBATCH 8
#define BROWS 256
#define KDIM 512
#define HIDD 512
#define GDIM 2048
#define KSTEP 32
#define NIT (KDIM / KSTEP)

typedef float f32x4 __attribute__((ext_vector_type(4)));
typedef __bf16 bf16x8 __attribute__((ext_vector_type(8)));

__device__ __forceinline__ unsigned fenc(float f) {
    unsigned u = __float_as_uint(f);
    return (u & 0x80000000u) ? ~u : (u | 0x80000000u);
}
__device__ __forceinline__ float fdec(unsigned e) {
    unsigned u = (e & 0x80000000u) ? (e & 0x7fffffffu) : ~e;
    return __uint_as_float(u);
}
__device__ __forceinline__ unsigned umaxu(unsigned a, unsigned b) { return a > b ? a : b; }

// quant(pact(x,a), 8, a)  -- all a's are powers of 2 so /a, *a are exact
__device__ __forceinline__ float qpact(float x, float a) {
    float ax = fabsf(x);
    float p  = copysignf(0.5f * (ax - fabsf(ax - a) + a), x);
    float x01 = p / a;
    x01 = fminf(fmaxf(x01, -0.9921875f), 0.9921875f);
    return (rintf(x01 * 128.f) * 0.0078125f) * a;
}
// quant(x, 8, 1.0)
__device__ __forceinline__ float q1(float x) {
    float x01 = fminf(fmaxf(x, -0.9921875f), 0.9921875f);
    return rintf(x01 * 128.f) * 0.0078125f;
}
__device__ __forceinline__ float sigmf(float x) { return 1.0f / (1.0f + expf(-x)); }

__global__ void k_init(unsigned* m) { if (threadIdx.x < 4) m[threadIdx.x] = 0u; }

__global__ void k_max(const float* __restrict__ w_ih, const float* __restrict__ w_hh,
                      const float* __restrict__ b_ih, const float* __restrict__ b_hh,
                      unsigned* __restrict__ omax) {
    int which = blockIdx.y;
    const float* src = which == 0 ? w_ih : which == 1 ? w_hh : which == 2 ? b_ih : b_hh;
    int n4 = (which < 2 ? NBATCH * KDIM * GDIM : NBATCH * GDIM) >> 2;
    unsigned best = 0u;
    int stride = gridDim.x * blockDim.x;
    for (int i = blockIdx.x * blockDim.x + threadIdx.x; i < n4; i += stride) {
        float4 v = ((const float4*)src)[i];
        best = umaxu(best, fenc(v.x)); best = umaxu(best, fenc(v.y));
        best = umaxu(best, fenc(v.z)); best = umaxu(best, fenc(v.w));
    }
    #pragma unroll
    for (int off = 32; off > 0; off >>= 1)
        best = umaxu(best, (unsigned)__shfl_down((int)best, off, 64));
    __shared__ unsigned red[4];
    int lane = threadIdx.x & 63, wv = threadIdx.x >> 6;
    if (lane == 0) red[wv] = best;
    __syncthreads();
    if (threadIdx.x == 0) {
        unsigned b2 = umaxu(umaxu(red[0], red[1]), umaxu(red[2], red[3]));
        atomicMax(&omax[which], b2);
    }
}

__global__ void k_prep(const float* __restrict__ input, const float* __restrict__ hx,
                       const float* __restrict__ bih, const float* __restrict__ bhh,
                       const float* __restrict__ nbih, const float* __restrict__ nbhh,
                       const float* __restrict__ a1, const unsigned* __restrict__ maxes,
                       __hip_bfloat16* __restrict__ xqh, __hip_bfloat16* __restrict__ hxh,
                       __hip_bfloat16* __restrict__ hxl, float* __restrict__ bias_comb) {
    const int NX = NBATCH * BROWS * KDIM;
    const int NH = NBATCH * BROWS * HIDD;
    const int NBC = NBATCH * GDIM;
    int total = NX + NH + NBC;
    int stride = gridDim.x * blockDim.x;
    for (int i = blockIdx.x * blockDim.x + threadIdx.x; i < total; i += stride) {
        if (i < NX) {
            int nb = i >> 17;              // /(256*512)
            int rem = i & 131071;
            float v = qpact(input[rem], a1[nb]);
            xqh[i] = __float2bfloat16(v);  // exact: integers <=127 for a1=128
        } else if (i < NX + NH) {
            int j = i - NX;
            float h = hx[j];
            __hip_bfloat16 hi = __float2bfloat16(h);
            hxh[j] = hi;
            hxl[j] = __float2bfloat16(h - __bfloat162float(hi));
        } else {
            int j = i - NX - NH;
            float mb_ih = fdec(maxes[2]);
            float mb_hh = fdec(maxes[3]);
            bias_comb[j] = q1(bih[j]) + (nbih[j] * mb_ih) * 0.05f
                         + q1(bhh[j]) + (nbhh[j] * mb_hh) * 0.05f;
        }
    }
}

__global__ __launch_bounds__(512, 2) void k_gemm(
    const float* __restrict__ w_ih, const float* __restrict__ w_hh,
    const float* __restrict__ n_ih, const float* __restrict__ n_hh,
    const __hip_bfloat16* __restrict__ xqh, const __hip_bfloat16* __restrict__ hxh,
    const __hip_bfloat16* __restrict__ hxl,
    const float* __restrict__ bias_comb, const float* __restrict__ cx,
    const float* __restrict__ a3, const float* __restrict__ a4, const float* __restrict__ a5,
    const float* __restrict__ a6, const float* __restrict__ a7, const float* __restrict__ a8,
    const float* __restrict__ a9, const float* __restrict__ a10, const float* __restrict__ a11,
    const unsigned* __restrict__ maxes,
    float* __restrict__ out_h, float* __restrict__ out_c)
{
    // double-buffered B tiles: [buf][mat][n=64][k=32 pad 40] bf16 -> 40 KB
    __shared__ __hip_bfloat16 Bsm[2][4][64][40];

    int tid = threadIdx.x;
    int lane = tid & 63, wv = tid >> 6;
    int nb = blockIdx.x & 7;        // batch -> XCD (round-robin) for A-operand L2 locality
    int cb = blockIdx.x >> 3;       // 32 column-blocks of 16 HID cols

    const float* wih_b = w_ih + nb * KDIM * GDIM;
    const float* whh_b = w_hh + nb * KDIM * GDIM;
    const float* nih_b = n_ih + nb * KDIM * GDIM;
    const float* nhh_b = n_hh + nb * KDIM * GDIM;
    const __hip_bfloat16* xq_b = xqh + nb * BROWS * KDIM;
    const __hip_bfloat16* hh_b = hxh + nb * BROWS * KDIM;
    const __hip_bfloat16* hl_b = hxl + nb * BROWS * KDIM;

    float c_ih = fdec(maxes[0]);
    float c_hh = fdec(maxes[1]);

    f32x4 acc[2][4] = {};

    int lh = lane & 15;
    int lk = (lane >> 4) << 3;      // k offset 0/8/16/24
    int m0 = wv << 5;               // 32 rows per wave

    // staging mapping: thread -> 4 consecutive n at one k
    int sn0 = (tid & 15) << 2;      // n base 0..60
    int sk  = tid >> 4;             // k 0..31
    int scol = ((sn0 >> 4) << 9) + (cb << 4) + (sn0 & 15);
    int sbase = sk * GDIM + scol;

    f32x4 rw1a, rz1a, rw2a, rz2a;
    f32x4 rw1b, rz1b, rw2b, rz2b;
    bf16x8 axv[2], ahv[2], alv[2];

#define STAGE(RW1, RZ1, RW2, RZ2, K0) {            \
    int gx = sbase + (K0) * GDIM;                  \
    RW1 = *(const f32x4*)(wih_b + gx);             \
    RZ1 = *(const f32x4*)(nih_b + gx);             \
    RW2 = *(const f32x4*)(whh_b + gx);             \
    RZ2 = *(const f32x4*)(nhh_b + gx); }

#define ALOAD(K0) {                                \
    _Pragma("unroll")                              \
    for (int mf = 0; mf < 2; ++mf) {               \
        int aoff = (m0 + (mf << 4) + lh) * KDIM + (K0) + lk; \
        axv[mf] = *(const bf16x8*)(xq_b + aoff);   \
        ahv[mf] = *(const bf16x8*)(hh_b + aoff);   \
        alv[mf] = *(const bf16x8*)(hl_b + aoff); } }

#define CVT(P, RW1, RZ1, RW2, RZ2) {               \
    _Pragma("unroll")                              \
    for (int j = 0; j < 4; ++j) {                  \
        float w1 = RW1[j], z1 = RZ1[j];            \
        float wq1 = rintf(fminf(fmaxf(w1, -0.9921875f), 0.9921875f) * 128.f) * 0.0078125f; \
        float e1 = wq1 + (z1 * c_ih) * 0.05f;      \
        __hip_bfloat16 h1 = __float2bfloat16(e1);  \
        Bsm[P][0][sn0 + j][sk] = h1;               \
        Bsm[P][1][sn0 + j][sk] = __float2bfloat16(e1 - __bfloat162float(h1)); \
        float w2 = RW2[j], z2 = RZ2[j];            \
        float wq2 = rintf(fminf(fmaxf(w2, -0.9921875f), 0.9921875f) * 128.f) * 0.0078125f; \
        float e2 = wq2 + (z2 * c_hh) * 0.05f;      \
        __hip_bfloat16 h2 = __float2bfloat16(e2);  \
        Bsm[P][2][sn0 + j][sk] = h2;               \
        Bsm[P][3][sn0 + j][sk] = __float2bfloat16(e2 - __bfloat162float(h2)); \
    } }

#define COMPUTE(P) {                               \
    _Pragma("unroll")                              \
    for (int nf = 0; nf < 4; ++nf) {               \
        int n = (nf << 4) + lh;                    \
        bf16x8 b0 = *(const bf16x8*)&Bsm[P][0][n][lk]; \
        bf16x8 b1 = *(const bf16x8*)&Bsm[P][1][n][lk]; \
        bf16x8 b2 = *(const bf16x8*)&Bsm[P][2][n][lk]; \
        bf16x8 b3 = *(const bf16x8*)&Bsm[P][3][n][lk]; \
        _Pragma("unroll")                          \
        for (int mf = 0; mf < 2; ++mf) {           \
            acc[mf][nf] = __builtin_amdgcn_mfma_f32_16x16x32_bf16(axv[mf], b0, acc[mf][nf], 0, 0, 0); \
            acc[mf][nf] = __builtin_amdgcn_mfma_f32_16x16x32_bf16(axv[mf], b1, acc[mf][nf], 0, 0, 0); \
            acc[mf][nf] = __builtin_amdgcn_mfma_f32_16x16x32_bf16(ahv[mf], b2, acc[mf][nf], 0, 0, 0); \
            acc[mf][nf] = __builtin_amdgcn_mfma_f32_16x16x32_bf16(ahv[mf], b3, acc[mf][nf], 0, 0, 0); \
            acc[mf][nf] = __builtin_amdgcn_mfma_f32_16x16x32_bf16(alv[mf], b2, acc[mf][nf], 0, 0, 0); \
        } \
    } }

    // prologue: prefetch staging for iters 0 and 1 (depth-2 pipeline)
    STAGE(rw1a, rz1a, rw2a, rz2a, 0);
    STAGE(rw1b, rz1b, rw2b, rz2b, KSTEP);

    for (int it = 0; it < NIT; it += 2) {
        // ---- half A: iter it (buffer 0) ----
        ALOAD(it * KSTEP);                               // issue early (L2)
        CVT(0, rw1a, rz1a, rw2a, rz2a);                  // waits staging set A
        if (it + 2 < NIT) STAGE(rw1a, rz1a, rw2a, rz2a, (it + 2) * KSTEP);
        __syncthreads();
        COMPUTE(0);
        // ---- half B: iter it+1 (buffer 1) ----
        ALOAD((it + 1) * KSTEP);
        CVT(1, rw1b, rz1b, rw2b, rz2b);
        if (it + 3 < NIT) STAGE(rw1b, rz1b, rw2b, rz2b, (it + 3) * KSTEP);
        __syncthreads();
        COMPUTE(1);
    }

    // fused epilogue: n-frag nf == gate index (i,j,f,o); all gates in-lane
    int hcol = (cb << 4) + lh;
    float A3 = a3[nb], A4 = a4[nb], A5 = a5[nb], A6 = a6[nb], A7 = a7[nb];
    float A8 = a8[nb], A9 = a9[nb], A10 = a10[nb], A11 = a11[nb];
    float bc_i = bias_comb[nb * GDIM + hcol];
    float bc_j = bias_comb[nb * GDIM + 512 + hcol];
    float bc_f = bias_comb[nb * GDIM + 1024 + hcol];
    float bc_o = bias_comb[nb * GDIM + 1536 + hcol];
    #pragma unroll
    for (int mf = 0; mf < 2; ++mf)
        #pragma unroll
        for (int rg = 0; rg < 4; ++rg) {
            int r = m0 + (mf << 4) + ((lane >> 4) << 2) + rg;
            float gi = acc[mf][0][rg] + bc_i;
            float gj = acc[mf][1][rg] + bc_j;
            float gf = acc[mf][2][rg] + bc_f;
            float go = acc[mf][3][rg] + bc_o;
            float fg = qpact(sigmf(gf), A3);
            float ig = qpact(sigmf(gi), A4);
            float act = qpact(tanhf(gj), A5);
            float og = qpact(sigmf(go), A6);
            int oidx = (nb * BROWS + r) * HIDD + hcol;
            float cv = cx[oidx];
            float gated = qpact(cv * fg, A7);
            float actin = qpact(ig * act, A8);
            float ncv = qpact(gated + actin, A9);
            float acv = qpact(tanhf(ncv), A10);
            float nhv = qpact(acv * og, A11);
            out_h[oidx] = nhv;
            out_c[oidx] = ncv;
        }
}

extern "C" void kernel_launch(void* const* d_in, const int* in_sizes, int n_in,
                              void* d_out, int out_size, void* d_ws, size_t ws_size,
                              hipStream_t stream) {
    const float* input = (const float*)d_in[0];
    const float* hx    = (const float*)d_in[1];
    const float* cx    = (const float*)d_in[2];
    const float* w_ih  = (const float*)d_in[3];
    const float* w_hh  = (const float*)d_in[4];
    const float* b_ih  = (const float*)d_in[5];
    const float* b_hh  = (const float*)d_in[6];
    const float* n_wih = (const float*)d_in[7];
    const float* n_whh = (const float*)d_in[8];
    const float* n_bih = (const float*)d_in[9];
    const float* n_bhh = (const float*)d_in[10];
    const float* a1  = (const float*)d_in[11];
    const float* a3  = (const float*)d_in[12];
    const float* a4  = (const float*)d_in[13];
    const float* a5  = (const float*)d_in[14];
    const float* a6  = (const float*)d_in[15];
    const float* a7  = (const float*)d_in[16];
    const float* a8  = (const float*)d_in[17];
    const float* a9  = (const float*)d_in[18];
    const float* a10 = (const float*)d_in[19];
    const float* a11 = (const float*)d_in[20];

    float* out_h = (float*)d_out;
    float* out_c = out_h + NBATCH * BROWS * HIDD;

    char* ws = (char*)d_ws;
    unsigned* maxes = (unsigned*)ws;
    __hip_bfloat16* xqh = (__hip_bfloat16*)(ws + 256);
    __hip_bfloat16* hxh = (__hip_bfloat16*)(ws + 256 + 2097152);
    __hip_bfloat16* hxl = (__hip_bfloat16*)(ws + 256 + 2 * 2097152);
    float* bias_comb    = (float*)(ws + 256 + 3 * 2097152);

    k_init<<<1, 64, 0, stream>>>(maxes);
    k_max<<<dim3(256, 4), 256, 0, stream>>>(w_ih, w_hh, b_ih, b_hh, maxes);
    k_prep<<<2048, 256, 0, stream>>>(input, hx, b_ih, b_hh, n_bih, n_bhh, a1, maxes,
                                     xqh, hxh, hxl, bias_comb);
    k_gemm<<<NBATCH * 32, 512, 0, stream>>>(w_ih, w_hh, n_wih, n_whh, xqh, hxh, hxl,
                                            bias_comb, cx,
                                            a3, a4, a5, a6, a7, a8, a9, a10, a11,
                                            maxes, out_h, out_c);
}